// Round 1
// baseline (1505.661 us; speedup 1.0000x reference)
//
#include <hip/hip_runtime.h>
#include <hip/hip_bf16.h>

#define DDIM 1024
#define BM 128
#define BN 128
#define BK 32
#define LDK 40  // bf16 elements per LDS row (32 + 8 pad -> 80B rows)

typedef __attribute__((ext_vector_type(4))) float floatx4;
typedef __attribute__((ext_vector_type(8))) short shortx8;
typedef __attribute__((ext_vector_type(4))) float floatv4;

// fp32 -> bf16 (RNE) via native __bf16 cast: compiler emits v_cvt_pk_bf16_f32
// (hand-rolled integer RNE defeats the HW converter and is ~4 VALU ops/elem).
static __device__ __forceinline__ short f2bf(float f) {
    union { __bf16 h; short s; } u;
    u.h = (__bf16)f;
    return u.s;
}

__global__ __launch_bounds__(256) void gather_bmm(
    const float* __restrict__ X, const int* __restrict__ steps,
    const float* __restrict__ Tm, float* __restrict__ out)
{
    __shared__ unsigned short As[BM * LDK];
    __shared__ unsigned short Bs[BN * LDK];

    const int tid = threadIdx.x;
    const int bx = blockIdx.x, by = blockIdx.y, b = blockIdx.z;
    const int idx = steps[b] - 1;

    const float* __restrict__ Ta = Tm + (size_t)idx * DDIM * DDIM + (size_t)(by * BM) * DDIM;
    const float* __restrict__ Xb = X + (size_t)b * DDIM * DDIM + bx * BN;
    float* __restrict__ Ob = out + (size_t)b * DDIM * DDIM;

    // A staging: thread handles rows am and am+64, k-octet akq (coalesced float4 pairs)
    const int am = tid >> 2;   // 0..63
    const int akq = tid & 3;   // 0..3 -> k offset akq*8
    // B staging: thread owns column nn, half kg of the 32 k-rows (transpose in-register)
    const int nn = tid & 127;
    const int kg = tid >> 7;   // 0/1 -> k rows kg*16 .. kg*16+15

    const int wave = tid >> 6, lane = tid & 63;
    const int wm = (wave >> 1) * 64, wn = (wave & 1) * 64;
    const int lrow = lane & 15, quad = lane >> 4;

    floatv4 acc[4][4];
#pragma unroll
    for (int i = 0; i < 4; ++i)
#pragma unroll
        for (int j = 0; j < 4; ++j)
            acc[i][j] = (floatv4){0.f, 0.f, 0.f, 0.f};

    floatx4 aR[2][2];
    float bR[16];

    const float* ap0 = Ta + (size_t)am * DDIM + akq * 8;
    const float* ap1 = ap0 + (size_t)64 * DDIM;
    const float* bp  = Xb + (size_t)(kg * 16) * DDIM + nn;

    // prologue: load tile k0 = 0
    aR[0][0] = *(const floatx4*)(ap0);
    aR[0][1] = *(const floatx4*)(ap0 + 4);
    aR[1][0] = *(const floatx4*)(ap1);
    aR[1][1] = *(const floatx4*)(ap1 + 4);
#pragma unroll
    for (int j = 0; j < 16; ++j) bR[j] = bp[(size_t)j * DDIM];

    for (int k0 = 0; k0 < DDIM; k0 += BK) {
        __syncthreads();  // previous iteration's LDS reads complete
        // ---- staged regs -> LDS (fp32 -> bf16 via v_cvt_pk_bf16_f32) ----
#pragma unroll
        for (int i = 0; i < 2; ++i) {
            float t[8];
            *(floatx4*)t = aR[i][0];
            *(floatx4*)(t + 4) = aR[i][1];
            shortx8 v;
#pragma unroll
            for (int e = 0; e < 8; ++e) v[e] = f2bf(t[e]);
            *(shortx8*)&As[(am + i * 64) * LDK + akq * 8] = v;
        }
        {
            shortx8 v0, v1;
#pragma unroll
            for (int e = 0; e < 8; ++e) v0[e] = f2bf(bR[e]);
#pragma unroll
            for (int e = 0; e < 8; ++e) v1[e] = f2bf(bR[e + 8]);
            *(shortx8*)&Bs[nn * LDK + kg * 16] = v0;
            *(shortx8*)&Bs[nn * LDK + kg * 16 + 8] = v1;
        }
        __syncthreads();
        // ---- prefetch next tile: global loads in flight during MFMA ----
        if (k0 + BK < DDIM) {
            const float* a0 = ap0 + k0 + BK;
            const float* a1 = ap1 + k0 + BK;
            aR[0][0] = *(const floatx4*)(a0);
            aR[0][1] = *(const floatx4*)(a0 + 4);
            aR[1][0] = *(const floatx4*)(a1);
            aR[1][1] = *(const floatx4*)(a1 + 4);
            const float* bq = bp + (size_t)(k0 + BK) * DDIM;
#pragma unroll
            for (int j = 0; j < 16; ++j) bR[j] = bq[(size_t)j * DDIM];
        }
        // ---- fragments + MFMA ----
        shortx8 af[4], bfrag[4];
#pragma unroll
        for (int i = 0; i < 4; ++i)
            af[i] = *(const shortx8*)&As[(wm + i * 16 + lrow) * LDK + quad * 8];
#pragma unroll
        for (int j = 0; j < 4; ++j)
            bfrag[j] = *(const shortx8*)&Bs[(wn + j * 16 + lrow) * LDK + quad * 8];
#pragma unroll
        for (int i = 0; i < 4; ++i)
#pragma unroll
            for (int j = 0; j < 4; ++j)
                acc[i][j] = __builtin_amdgcn_mfma_f32_16x16x32_bf16(
                    af[i], bfrag[j], acc[i][j], 0, 0, 0);
    }

    // ---- epilogue: C/D layout col=lane&15, row=quad*4+reg ----
    // non-temporal: C is write-once, keep it out of L2 so T/X panels stay cached
#pragma unroll
    for (int i = 0; i < 4; ++i) {
        const int row0 = by * BM + wm + i * 16 + quad * 4;
#pragma unroll
        for (int j = 0; j < 4; ++j) {
            const int col = bx * BN + wn + j * 16 + lrow;
#pragma unroll
            for (int r = 0; r < 4; ++r)
                __builtin_nontemporal_store(acc[i][j][r],
                    &Ob[(size_t)(row0 + r) * DDIM + col]);
        }
    }
}

extern "C" void kernel_launch(void* const* d_in, const int* in_sizes, int n_in,
                              void* d_out, int out_size, void* d_ws, size_t ws_size,
                              hipStream_t stream) {
    const float* X     = (const float*)d_in[0];
    const int*   steps = (const int*)d_in[1];
    const float* Tm    = (const float*)d_in[2];
    float* out = (float*)d_out;
    const int nb = in_sizes[1];  // batch = number of fwd_steps entries (128)
    dim3 grid(DDIM / BN, DDIM / BM, nb);
    gather_bmm<<<grid, 256, 0, stream>>>(X, steps, Tm, out);
}

// Round 2
// 1435.623 us; speedup vs baseline: 1.0488x; 1.0488x over previous
//
#include <hip/hip_runtime.h>
#include <hip/hip_bf16.h>

#define DDIM 1024
#define BM 128
#define BN 128
#define BK 32
#define NT (DDIM / BK)   // 32 k-tiles
#define LDK 40           // bf16 elements per LDS row (32 + 8 pad -> 80B rows)

typedef __attribute__((ext_vector_type(4))) float floatx4;
typedef __attribute__((ext_vector_type(8))) short shortx8;
typedef __attribute__((ext_vector_type(4))) float floatv4;

// fp32 -> bf16 (RNE) via native __bf16 cast: compiler emits v_cvt_pk_bf16_f32
static __device__ __forceinline__ short f2bf(float f) {
    union { __bf16 h; short s; } u;
    u.h = (__bf16)f;
    return u.s;
}

// Load one BK-wide k-tile of A (2 row-halves x 8 floats) and B (16 strided rows)
#define LOAD_TILE(aR, bR, KT)                                        \
  { const float* a0_ = ap0 + (KT) * BK;                              \
    const float* a1_ = ap1 + (KT) * BK;                              \
    aR[0][0] = *(const floatx4*)(a0_);                               \
    aR[0][1] = *(const floatx4*)(a0_ + 4);                           \
    aR[1][0] = *(const floatx4*)(a1_);                               \
    aR[1][1] = *(const floatx4*)(a1_ + 4);                           \
    const float* bq_ = bp + (size_t)((KT) * BK) * DDIM;              \
    _Pragma("unroll")                                                \
    for (int j = 0; j < 16; ++j) bR[j] = bq_[(size_t)j * DDIM]; }

// One K-step: LDS-write staged tile, prefetch tile KN into same (named) regs,
// then fragment reads + 16 MFMA. Depth-2: KN = current + 2.
#define STEP(aR, bR, KN)                                             \
  { __syncthreads();                                                 \
    _Pragma("unroll")                                                \
    for (int i = 0; i < 2; ++i) {                                    \
      float tt[8];                                                   \
      *(floatx4*)tt = aR[i][0]; *(floatx4*)(tt + 4) = aR[i][1];      \
      shortx8 v;                                                     \
      _Pragma("unroll")                                              \
      for (int e = 0; e < 8; ++e) v[e] = f2bf(tt[e]);                \
      *(shortx8*)&As[(am + i * 64) * LDK + akq * 8] = v;             \
    }                                                                \
    { shortx8 v0, v1;                                                \
      _Pragma("unroll")                                              \
      for (int e = 0; e < 8; ++e) v0[e] = f2bf(bR[e]);               \
      _Pragma("unroll")                                              \
      for (int e = 0; e < 8; ++e) v1[e] = f2bf(bR[e + 8]);           \
      *(shortx8*)&Bs[nn * LDK + kg * 16] = v0;                       \
      *(shortx8*)&Bs[nn * LDK + kg * 16 + 8] = v1;                   \
    }                                                                \
    if ((KN) < NT) LOAD_TILE(aR, bR, KN);                            \
    __syncthreads();                                                 \
    shortx8 af_[4], bf_[4];                                          \
    _Pragma("unroll")                                                \
    for (int i = 0; i < 4; ++i)                                      \
      af_[i] = *(const shortx8*)&As[(wm + i * 16 + lrow) * LDK + quad * 8]; \
    _Pragma("unroll")                                                \
    for (int j = 0; j < 4; ++j)                                      \
      bf_[j] = *(const shortx8*)&Bs[(wn + j * 16 + lrow) * LDK + quad * 8]; \
    _Pragma("unroll")                                                \
    for (int i = 0; i < 4; ++i)                                      \
      _Pragma("unroll")                                              \
      for (int j = 0; j < 4; ++j)                                    \
        acc[i][j] = __builtin_amdgcn_mfma_f32_16x16x32_bf16(         \
            af_[i], bf_[j], acc[i][j], 0, 0, 0); }

__global__ __launch_bounds__(256) void gather_bmm(
    const float* __restrict__ X, const int* __restrict__ steps,
    const float* __restrict__ Tm, float* __restrict__ out)
{
    __shared__ unsigned short As[BM * LDK];
    __shared__ unsigned short Bs[BN * LDK];

    const int tid = threadIdx.x;

    // ---- bijective XCD-aware swizzle (m204): each XCD gets a contiguous
    // chunk of whole batches -> batch's T matrix (4MB) + X panels L2-resident.
    const int nwg = gridDim.x;
    const int orig = blockIdx.x;
    const int q = nwg >> 3, r = nwg & 7;
    const int xcd = orig & 7, pos = orig >> 3;
    const int wg = (xcd < r ? xcd * (q + 1) : r * (q + 1) + (xcd - r) * q) + pos;
    const int b  = wg >> 6;          // 64 blocks per batch (8x8 tile grid)
    const int t6 = wg & 63;
    const int by = t6 >> 3, bx = t6 & 7;

    const int idx = steps[b] - 1;

    const float* __restrict__ Ta = Tm + (size_t)idx * DDIM * DDIM + (size_t)(by * BM) * DDIM;
    const float* __restrict__ Xb = X + (size_t)b * DDIM * DDIM + bx * BN;
    float* __restrict__ Ob = out + (size_t)b * DDIM * DDIM;

    // A staging: thread handles rows am and am+64, k-octet akq
    const int am = tid >> 2;   // 0..63
    const int akq = tid & 3;   // 0..3 -> k offset akq*8
    // B staging: thread owns column nn, half kg of the 32 k-rows
    const int nn = tid & 127;
    const int kg = tid >> 7;

    const int wave = tid >> 6, lane = tid & 63;
    const int wm = (wave >> 1) * 64, wn = (wave & 1) * 64;
    const int lrow = lane & 15, quad = lane >> 4;

    floatv4 acc[4][4];
#pragma unroll
    for (int i = 0; i < 4; ++i)
#pragma unroll
        for (int j = 0; j < 4; ++j)
            acc[i][j] = (floatv4){0.f, 0.f, 0.f, 0.f};

    const float* ap0 = Ta + (size_t)am * DDIM + akq * 8;
    const float* ap1 = ap0 + (size_t)64 * DDIM;
    const float* bp  = Xb + (size_t)(kg * 16) * DDIM + nn;

    // depth-2 staging: two NAMED register buffers (rule #20: no runtime
    // indexing of ext_vector arrays -> scratch)
    floatx4 aP[2][2], aQ[2][2];
    float   bP[16],   bQ[16];

    LOAD_TILE(aP, bP, 0);
    LOAD_TILE(aQ, bQ, 1);

    for (int kt = 0; kt < NT; kt += 2) {
        STEP(aP, bP, kt + 2);
        STEP(aQ, bQ, kt + 3);
    }

    // ---- epilogue: C/D layout col=lane&15, row=quad*4+reg ----
    // non-temporal: C is write-once, keep L2 for T/X panels
#pragma unroll
    for (int i = 0; i < 4; ++i) {
        const int row0 = by * BM + wm + i * 16 + quad * 4;
#pragma unroll
        for (int j = 0; j < 4; ++j) {
            const int col = bx * BN + wn + j * 16 + lrow;
#pragma unroll
            for (int rr = 0; rr < 4; ++rr)
                __builtin_nontemporal_store(acc[i][j][rr],
                    &Ob[(size_t)(row0 + rr) * DDIM + col]);
        }
    }
}

extern "C" void kernel_launch(void* const* d_in, const int* in_sizes, int n_in,
                              void* d_out, int out_size, void* d_ws, size_t ws_size,
                              hipStream_t stream) {
    const float* X     = (const float*)d_in[0];
    const int*   steps = (const int*)d_in[1];
    const float* Tm    = (const float*)d_in[2];
    float* out = (float*)d_out;
    const int nb = in_sizes[1];  // batch count (128)
    const int total = nb * (DDIM / BM) * (DDIM / BN);  // 64 blocks/batch
    gather_bmm<<<dim3(total), 256, 0, stream>>>(X, steps, Tm, out);
}